// Round 4
// baseline (807.246 us; speedup 1.0000x reference)
//
#include <hip/hip_runtime.h>
#include <hip/hip_bf16.h>
#include <stdint.h>

#define NH   16
#define EMB  1024
#define HD   64
#define BSZ  2
#define SEQ  2048

// ---------- bf16 helpers (OCP bf16 = upper 16 bits of fp32) ----------
__device__ __forceinline__ float bf2f(uint32_t u16) {
    union { uint32_t i; float f; } v; v.i = u16 << 16; return v.f;
}
__device__ __forceinline__ uint16_t f2bf(float f) {
    union { float f; uint32_t i; } v; v.f = f;
    uint32_t r = v.i + 0x7FFFu + ((v.i >> 16) & 1u);  // round-to-nearest-even
    return (uint16_t)(r >> 16);
}
__device__ __forceinline__ void bf4_to_f(uint2 r, float* o) {
    o[0] = bf2f(r.x & 0xFFFFu);
    o[1] = bf2f(r.x >> 16);
    o[2] = bf2f(r.y & 0xFFFFu);
    o[3] = bf2f(r.y >> 16);
}

// ---------- dtype-agnostic 4-element load/store (idx must be %4==0) ----------
__device__ __forceinline__ void load4(const void* base, size_t idx, int isf32, float* o) {
    if (isf32) {
        float4 v = *(const float4*)((const float*)base + idx);
        o[0] = v.x; o[1] = v.y; o[2] = v.z; o[3] = v.w;
    } else {
        uint2 r = *(const uint2*)((const uint16_t*)base + idx);
        bf4_to_f(r, o);
    }
}
__device__ __forceinline__ void store4(void* base, size_t idx, int isf32, const float* v) {
    if (isf32) {
        *(float4*)((float*)base + idx) = make_float4(v[0], v[1], v[2], v[3]);
    } else {
        ushort4 u;
        u.x = f2bf(v[0]); u.y = f2bf(v[1]); u.z = f2bf(v[2]); u.w = f2bf(v[3]);
        *(ushort4*)((uint16_t*)base + idx) = u;
    }
}

// =====================================================================
// Kernel 0: dtype sniffer. One wave reads X's first 64 words. If the low
// 16 bits of each word decode to a plausible N(0,1) bf16 (biased exp in
// [114,130]) the buffer is packed bf16; fp32 low-halves are uniform
// mantissa bits (~7% pass rate). Ballot-vote, threshold 32/64.
// flag = 1 -> fp32, 0 -> bf16.
// =====================================================================
__global__ void dtype_sniff(const uint32_t* __restrict__ X, int* __restrict__ flag) {
    const int tid = threadIdx.x;   // 64 threads
    uint32_t w = X[tid];
    uint32_t lo = w & 0xFFFFu;
    uint32_t e = (lo >> 7) & 0xFFu;
    bool plausible = (e >= 114u && e <= 130u) || (lo == 0u);
    unsigned long long m = __ballot(plausible);
    if (tid == 0) *flag = (__popcll(m) < 32) ? 1 : 0;
}

// =====================================================================
// Kernel 1: projection GEMM.  C = X[4096,1024] @ W.
// bx: 0..15 -> 64-col tiles of Q (into d_out, I/O dtype), 16 -> K, 17 -> V
// (K/V stored as canonical fp32 in d_ws).  grid.y: 64 row-tiles.
// 256 threads, 4x4 microtile per thread.
// =====================================================================
__global__ __launch_bounds__(256) void qkv_gemm(
    const void* __restrict__ X,  const void* __restrict__ Wq,
    const void* __restrict__ Wk, const void* __restrict__ Wv,
    void* __restrict__ Qout, float* __restrict__ Kws,
    float* __restrict__ Vws, const int* __restrict__ flag)
{
    const int isf32 = *flag;
    const int tid = threadIdx.x;
    const int tx = tid & 15, ty = tid >> 4;
    const int bx = blockIdx.x;
    const int m0 = blockIdx.y * 64;

    const void* W; int ldw, n0;
    float* fout = nullptr;             // fp32 K/V destination (ws)
    if (bx < 16)       { W = Wq; ldw = EMB; n0 = bx * 64; }
    else if (bx == 16) { W = Wk; ldw = HD;  n0 = 0; fout = Kws; }
    else               { W = Wv; ldw = HD;  n0 = 0; fout = Vws; }

    __shared__ float sA[64][17];   // X tile  [m][k]
    __shared__ float sB[16][64];   // W tile  [k][n]

    float acc[4][4] = {};

    const int arow = tid >> 2, acol = (tid & 3) * 4;   // 64 rows x 16 k
    const int brow = tid >> 4, bcol = (tid & 15) * 4;  // 16 k   x 64 n

    for (int k0 = 0; k0 < EMB; k0 += 16) {
        float fa[4], fb[4];
        load4(X, (size_t)(m0 + arow) * EMB + k0 + acol, isf32, fa);
        load4(W, (size_t)(k0 + brow) * ldw + n0 + bcol, isf32, fb);
        sA[arow][acol + 0] = fa[0]; sA[arow][acol + 1] = fa[1];
        sA[arow][acol + 2] = fa[2]; sA[arow][acol + 3] = fa[3];
        sB[brow][bcol + 0] = fb[0]; sB[brow][bcol + 1] = fb[1];
        sB[brow][bcol + 2] = fb[2]; sB[brow][bcol + 3] = fb[3];
        __syncthreads();
#pragma unroll
        for (int kk = 0; kk < 16; ++kk) {
            float a0 = sA[4 * ty + 0][kk];
            float a1 = sA[4 * ty + 1][kk];
            float a2 = sA[4 * ty + 2][kk];
            float a3 = sA[4 * ty + 3][kk];
            float4 b = *(const float4*)&sB[kk][4 * tx];
            acc[0][0] += a0 * b.x; acc[0][1] += a0 * b.y; acc[0][2] += a0 * b.z; acc[0][3] += a0 * b.w;
            acc[1][0] += a1 * b.x; acc[1][1] += a1 * b.y; acc[1][2] += a1 * b.z; acc[1][3] += a1 * b.w;
            acc[2][0] += a2 * b.x; acc[2][1] += a2 * b.y; acc[2][2] += a2 * b.z; acc[2][3] += a2 * b.w;
            acc[3][0] += a3 * b.x; acc[3][1] += a3 * b.y; acc[3][2] += a3 * b.z; acc[3][3] += a3 * b.w;
        }
        __syncthreads();
    }

#pragma unroll
    for (int i = 0; i < 4; ++i) {
        if (fout) {  // K or V -> fp32 workspace
            *(float4*)&fout[(size_t)(m0 + 4 * ty + i) * HD + 4 * tx] =
                make_float4(acc[i][0], acc[i][1], acc[i][2], acc[i][3]);
        } else {     // Q -> d_out in I/O dtype
            store4(Qout, (size_t)(m0 + 4 * ty + i) * EMB + n0 + 4 * tx, isf32, acc[i]);
        }
    }
}

// =====================================================================
// Kernel 2: causal MQA flash attention, fp32 accumulate.
// One block per (b, h, 64-row Q tile).  256 threads.
// Q read from d_out (each block touches only the region it overwrites).
// K/V read as fp32 from d_ws.
// =====================================================================
__global__ __launch_bounds__(256) void mqa_attn(
    const float* __restrict__ Kws, const float* __restrict__ Vws,
    void* __restrict__ Out, const int* __restrict__ flag)
{
    const int isf32 = *flag;
    const int tid = threadIdx.x;
    const int tx = tid & 15, ty = tid >> 4;
    const int qb = blockIdx.x;        // 0..31
    const int h  = blockIdx.y;        // 0..15
    const int b  = blockIdx.z;        // 0..1
    const int q0 = qb * 64;
    const int r0 = 4 * ty;

    __shared__ float Qs[64][68];      // Q tile [r][d]
    __shared__ float KV[64][68];      // K tile [t][d], then V tile [t][d]
    __shared__ float P [64][68];      // scores / probs [r][t]
    __shared__ float rowtmp[64];      // alpha, then 1/l

    // ---- load Q tile from d_out ----
    for (int it = 0; it < 4; ++it) {
        int lin = it * 1024 + tid * 4;
        int r = lin >> 6, d = lin & 63;
        float f[4];
        load4(Out, (size_t)(b * SEQ + q0 + r) * EMB + h * HD + d, isf32, f);
        Qs[r][d + 0] = f[0]; Qs[r][d + 1] = f[1];
        Qs[r][d + 2] = f[2]; Qs[r][d + 3] = f[3];
    }

    float m_r = -1e30f, l_r = 0.f;
    float O[4][4] = {};
    const float scale = 0.125f;   // 1/sqrt(64)

    for (int kb = 0; kb <= qb; ++kb) {
        const int k0 = kb * 64;

        __syncthreads();   // prev O-phase done with KV; also fences Qs load
        // ---- load K tile (fp32 ws) ----
        for (int it = 0; it < 4; ++it) {
            int lin = it * 1024 + tid * 4;
            int t = lin >> 6, d = lin & 63;
            float4 v = *(const float4*)&Kws[(size_t)(b * SEQ + k0 + t) * HD + d];
            KV[t][d + 0] = v.x; KV[t][d + 1] = v.y;
            KV[t][d + 2] = v.z; KV[t][d + 3] = v.w;
        }
        __syncthreads();

        // ---- S = Q K^T ----
        float acc[4][4] = {};
        for (int d4 = 0; d4 < HD; d4 += 4) {
            float4 qv[4], kv4[4];
#pragma unroll
            for (int i = 0; i < 4; ++i) qv[i] = *(const float4*)&Qs[r0 + i][d4];
#pragma unroll
            for (int j = 0; j < 4; ++j) kv4[j] = *(const float4*)&KV[tx + 16 * j][d4];
#pragma unroll
            for (int i = 0; i < 4; ++i)
#pragma unroll
                for (int j = 0; j < 4; ++j)
                    acc[i][j] += qv[i].x * kv4[j].x + qv[i].y * kv4[j].y
                               + qv[i].z * kv4[j].z + qv[i].w * kv4[j].w;
        }
        const bool diag = (kb == qb);
#pragma unroll
        for (int i = 0; i < 4; ++i)
#pragma unroll
            for (int j = 0; j < 4; ++j) {
                int c = tx + 16 * j;
                float s = acc[i][j] * scale;
                if (diag && c > r0 + i) s = -1e30f;   // causal mask (tile-local)
                P[r0 + i][c] = s;
            }
        __syncthreads();

        // ---- softmax rows (wave 0) | V load (waves 1..3) ----
        if (tid < 64) {
            const int r = tid;
            float mx = m_r;
            for (int c = 0; c < 64; c += 4) {
                float4 p4 = *(const float4*)&P[r][c];
                mx = fmaxf(mx, fmaxf(fmaxf(p4.x, p4.y), fmaxf(p4.z, p4.w)));
            }
            float alpha = __expf(m_r - mx);
            float sum = 0.f;
            for (int c = 0; c < 64; c += 4) {
                float4 p4 = *(const float4*)&P[r][c];
                p4.x = __expf(p4.x - mx); p4.y = __expf(p4.y - mx);
                p4.z = __expf(p4.z - mx); p4.w = __expf(p4.w - mx);
                sum += p4.x + p4.y + p4.z + p4.w;
                *(float4*)&P[r][c] = p4;
            }
            m_r = mx;
            l_r = alpha * l_r + sum;
            rowtmp[r] = alpha;
        } else {
            for (int c = tid - 64; c < 1024; c += 192) {
                int lin = c * 4;
                int t = lin >> 6, d = lin & 63;
                float4 v = *(const float4*)&Vws[(size_t)(b * SEQ + k0 + t) * HD + d];
                KV[t][d + 0] = v.x; KV[t][d + 1] = v.y;
                KV[t][d + 2] = v.z; KV[t][d + 3] = v.w;
            }
        }
        __syncthreads();

        // ---- O = diag(alpha) O + P V ----
        float al0 = rowtmp[r0 + 0], al1 = rowtmp[r0 + 1];
        float al2 = rowtmp[r0 + 2], al3 = rowtmp[r0 + 3];
#pragma unroll
        for (int j = 0; j < 4; ++j) {
            O[0][j] *= al0; O[1][j] *= al1; O[2][j] *= al2; O[3][j] *= al3;
        }
        for (int t = 0; t < 64; ++t) {
            float4 v4 = *(const float4*)&KV[t][4 * tx];
            float p0 = P[r0 + 0][t], p1 = P[r0 + 1][t];
            float p2 = P[r0 + 2][t], p3 = P[r0 + 3][t];
            O[0][0] += p0 * v4.x; O[0][1] += p0 * v4.y; O[0][2] += p0 * v4.z; O[0][3] += p0 * v4.w;
            O[1][0] += p1 * v4.x; O[1][1] += p1 * v4.y; O[1][2] += p1 * v4.z; O[1][3] += p1 * v4.w;
            O[2][0] += p2 * v4.x; O[2][1] += p2 * v4.y; O[2][2] += p2 * v4.z; O[2][3] += p2 * v4.w;
            O[3][0] += p3 * v4.x; O[3][1] += p3 * v4.y; O[3][2] += p3 * v4.z; O[3][3] += p3 * v4.w;
        }
    }

    // ---- finalize: divide by l, overwrite this block's Q region with O ----
    __syncthreads();
    if (tid < 64) rowtmp[tid] = 1.0f / l_r;
    __syncthreads();
#pragma unroll
    for (int i = 0; i < 4; ++i) {
        float inv = rowtmp[r0 + i];
        float o4[4] = { O[i][0] * inv, O[i][1] * inv, O[i][2] * inv, O[i][3] * inv };
        store4(Out, (size_t)(b * SEQ + q0 + r0 + i) * EMB + h * HD + 4 * tx, isf32, o4);
    }
}

extern "C" void kernel_launch(void* const* d_in, const int* in_sizes, int n_in,
                              void* d_out, int out_size, void* d_ws, size_t ws_size,
                              hipStream_t stream) {
    const void* X  = d_in[0];
    const void* Wq = d_in[1];
    const void* Wk = d_in[2];
    const void* Wv = d_in[3];

    // Workspace layout: [0..15] dtype flag; then K, V as fp32 (1 MiB each).
    int*   flag = (int*)d_ws;
    float* Kws  = (float*)((char*)d_ws + 16);
    float* Vws  = Kws + (size_t)BSZ * SEQ * HD;

    dtype_sniff<<<1, 64, 0, stream>>>((const uint32_t*)X, flag);
    qkv_gemm<<<dim3(18, 64), 256, 0, stream>>>(X, Wq, Wk, Wv, d_out, Kws, Vws, flag);
    mqa_attn<<<dim3(SEQ / 64, NH, BSZ), 256, 0, stream>>>(Kws, Vws, d_out, flag);
}

// Round 5
// 306.337 us; speedup vs baseline: 2.6352x; 2.6352x over previous
//
#include <hip/hip_runtime.h>
#include <stdint.h>

#define NH   16
#define EMB  1024
#define HD   64
#define BSZ  2
#define SEQ  2048

typedef __attribute__((ext_vector_type(8))) short bf16x8;   // 8 bf16 = 4 VGPRs
typedef __attribute__((ext_vector_type(4))) float f32x4;    // MFMA C/D

__device__ __forceinline__ uint16_t f2bf(float f) {
    union { float f; uint32_t i; } v; v.f = f;
    uint32_t r = v.i + 0x7FFFu + ((v.i >> 16) & 1u);  // RNE
    return (uint16_t)(r >> 16);
}
__device__ __forceinline__ uint32_t pack2(float a, float b) {
    return (uint32_t)f2bf(a) | ((uint32_t)f2bf(b) << 16);
}

// =====================================================================
// Kernel 1: projection GEMM (fp32 vector core, unchanged from passing R4).
// bx 0..15 -> Q cols (fp32 into d_out); bx 16 -> K (bf16 [t][d] in ws);
// bx 17 -> V (bf16 TRANSPOSED Vt[d][t] in ws, MFMA-B-ready).
// =====================================================================
__global__ __launch_bounds__(256) void qkv_gemm(
    const float* __restrict__ X,  const float* __restrict__ Wq,
    const float* __restrict__ Wk, const float* __restrict__ Wv,
    float* __restrict__ Qout, uint16_t* __restrict__ Kbf,
    uint16_t* __restrict__ Vtbf)
{
    const int tid = threadIdx.x;
    const int tx = tid & 15, ty = tid >> 4;
    const int bx = blockIdx.x;
    const int m0 = blockIdx.y * 64;

    const float* W; int ldw, n0;
    if (bx < 16)       { W = Wq; ldw = EMB; n0 = bx * 64; }
    else if (bx == 16) { W = Wk; ldw = HD;  n0 = 0; }
    else               { W = Wv; ldw = HD;  n0 = 0; }

    __shared__ float sA[64][17];   // X tile [m][k]
    __shared__ float sB[16][64];   // W tile [k][n]

    float acc[4][4] = {};
    const int arow = tid >> 2, acol = (tid & 3) * 4;   // 64 rows x 16 k
    const int brow = tid >> 4, bcol = (tid & 15) * 4;  // 16 k   x 64 n

    for (int k0 = 0; k0 < EMB; k0 += 16) {
        float4 fa = *(const float4*)&X[(size_t)(m0 + arow) * EMB + k0 + acol];
        float4 fb = *(const float4*)&W[(size_t)(k0 + brow) * ldw + n0 + bcol];
        sA[arow][acol + 0] = fa.x; sA[arow][acol + 1] = fa.y;
        sA[arow][acol + 2] = fa.z; sA[arow][acol + 3] = fa.w;
        sB[brow][bcol + 0] = fb.x; sB[brow][bcol + 1] = fb.y;
        sB[brow][bcol + 2] = fb.z; sB[brow][bcol + 3] = fb.w;
        __syncthreads();
#pragma unroll
        for (int kk = 0; kk < 16; ++kk) {
            float a0 = sA[4 * ty + 0][kk];
            float a1 = sA[4 * ty + 1][kk];
            float a2 = sA[4 * ty + 2][kk];
            float a3 = sA[4 * ty + 3][kk];
            float4 b = *(const float4*)&sB[kk][4 * tx];
            acc[0][0] += a0 * b.x; acc[0][1] += a0 * b.y; acc[0][2] += a0 * b.z; acc[0][3] += a0 * b.w;
            acc[1][0] += a1 * b.x; acc[1][1] += a1 * b.y; acc[1][2] += a1 * b.z; acc[1][3] += a1 * b.w;
            acc[2][0] += a2 * b.x; acc[2][1] += a2 * b.y; acc[2][2] += a2 * b.z; acc[2][3] += a2 * b.w;
            acc[3][0] += a3 * b.x; acc[3][1] += a3 * b.y; acc[3][2] += a3 * b.z; acc[3][3] += a3 * b.w;
        }
        __syncthreads();
    }

    if (bx < 16) {            // Q -> fp32 d_out
#pragma unroll
        for (int i = 0; i < 4; ++i)
            *(float4*)&Qout[(size_t)(m0 + 4 * ty + i) * EMB + n0 + 4 * tx] =
                make_float4(acc[i][0], acc[i][1], acc[i][2], acc[i][3]);
    } else if (bx == 16) {    // K -> bf16 [t][d]
#pragma unroll
        for (int i = 0; i < 4; ++i) {
            ushort4 u; u.x = f2bf(acc[i][0]); u.y = f2bf(acc[i][1]);
            u.z = f2bf(acc[i][2]); u.w = f2bf(acc[i][3]);
            *(ushort4*)&Kbf[(size_t)(m0 + 4 * ty + i) * HD + 4 * tx] = u;
        }
    } else {                  // V -> bf16 transposed Vt[d][t]
#pragma unroll
        for (int j = 0; j < 4; ++j) {
            ushort4 u; u.x = f2bf(acc[0][j]); u.y = f2bf(acc[1][j]);
            u.z = f2bf(acc[2][j]); u.w = f2bf(acc[3][j]);
            *(ushort4*)&Vtbf[(size_t)(4 * tx + j) * (BSZ * SEQ) + m0 + 4 * ty] = u;
        }
    }
}

// =====================================================================
// Kernel 2: causal MQA flash attention with bf16 MFMA (16x16x32).
// Block = (qb, h, b), 256 threads = 4 waves; wave w owns Q rows [16w,16w+16).
// S^T = K·Q^T (softmax in-lane along C-layout rows), P^T packed to LDS
// P[m][t] via contiguous b64 writes (wave-private), O = P·V.
// LDS rows padded to 72 bf16 -> conflict-free b128 frag reads.
// =====================================================================
__global__ __launch_bounds__(256, 4) void mqa_attn(
    const uint16_t* __restrict__ Kbf, const uint16_t* __restrict__ Vtbf,
    float* __restrict__ Out)
{
    const int tid  = threadIdx.x;
    const int w    = tid >> 6;        // wave 0..3
    const int lane = tid & 63;
    const int l    = lane & 15;       // 16-index within fragment
    const int quad = lane >> 4;       // 0..3
    const int qb = blockIdx.x, h = blockIdx.y, b = blockIdx.z;
    const int q0 = qb * 64;

    __shared__ uint16_t Qs [64][72];  // Q  bf16 [m][d]
    __shared__ uint16_t Ks [64][72];  // K  bf16 [t][d]
    __shared__ uint16_t Vts[64][72];  // V^T bf16 [d][t]
    __shared__ uint16_t Ps [64][72];  // P  bf16 [m][t] (wave-private rows)

    // ---- stage Q: fp32 d_out -> bf16 LDS ----
    {
        const int r = tid >> 2, c0 = (tid & 3) * 16;
        const float* src = &Out[(size_t)(b * SEQ + q0 + r) * EMB + h * HD + c0];
        float4 f0 = *(const float4*)(src + 0);
        float4 f1 = *(const float4*)(src + 4);
        float4 f2 = *(const float4*)(src + 8);
        float4 f3 = *(const float4*)(src + 12);
        *(uint4*)&Qs[r][c0] =
            make_uint4(pack2(f0.x, f0.y), pack2(f0.z, f0.w),
                       pack2(f1.x, f1.y), pack2(f1.z, f1.w));
        *(uint4*)&Qs[r][c0 + 8] =
            make_uint4(pack2(f2.x, f2.y), pack2(f2.z, f2.w),
                       pack2(f3.x, f3.y), pack2(f3.z, f3.w));
    }
    __syncthreads();

    // Q B-fragments: B[k=d][n=m] -> Qs[16w + l][d], persistent across kb
    bf16x8 qf0 = *(const bf16x8*)&Qs[16 * w + l][quad * 8];
    bf16x8 qf1 = *(const bf16x8*)&Qs[16 * w + l][32 + quad * 8];

    float m_r = -1e30f, l_r = 0.f;
    f32x4 accO[4] = {{0.f,0.f,0.f,0.f},{0.f,0.f,0.f,0.f},
                     {0.f,0.f,0.f,0.f},{0.f,0.f,0.f,0.f}};
    const float C = 0.125f * 1.4426950408889634f;   // scale * log2(e)
    const int qi_l = 16 * w + l;                    // block-local query row

    for (int kb = 0; kb <= qb; ++kb) {
        const int k0 = kb * 64;
        __syncthreads();   // prev iter's PV done reading Vts/Ks

        // ---- stage K tile [t][d] and Vt tile [d][t] (bf16 copies) ----
        {
            const int r = tid >> 2, c0 = (tid & 3) * 16;
            const uint4* ks = (const uint4*)&Kbf[(size_t)(b * SEQ + k0 + r) * HD + c0];
            uint4 k0v = ks[0], k1v = ks[1];
            *(uint4*)&Ks[r][c0] = k0v; *(uint4*)&Ks[r][c0 + 8] = k1v;
            const uint4* vs = (const uint4*)&Vtbf[(size_t)r * (BSZ * SEQ) + b * SEQ + k0 + c0];
            uint4 v0v = vs[0], v1v = vs[1];
            *(uint4*)&Vts[r][c0] = v0v; *(uint4*)&Vts[r][c0 + 8] = v1v;
        }
        __syncthreads();

        // ---- S^T = K · Q^T : 4 t-strips x 2 k-halves ----
        f32x4 accS[4] = {{0.f,0.f,0.f,0.f},{0.f,0.f,0.f,0.f},
                         {0.f,0.f,0.f,0.f},{0.f,0.f,0.f,0.f}};
#pragma unroll
        for (int ts = 0; ts < 4; ++ts) {
            bf16x8 a0 = *(const bf16x8*)&Ks[16 * ts + l][quad * 8];
            bf16x8 a1 = *(const bf16x8*)&Ks[16 * ts + l][32 + quad * 8];
            accS[ts] = __builtin_amdgcn_mfma_f32_16x16x32_bf16(a0, qf0, accS[ts], 0, 0, 0);
            accS[ts] = __builtin_amdgcn_mfma_f32_16x16x32_bf16(a1, qf1, accS[ts], 0, 0, 0);
        }

        // ---- online softmax along t (in-lane 16 + shfl_xor 16/32) ----
        // D-layout: col = l = query m; row = quad*4+reg = t within strip.
        float sv[16];
        float tmax = -1e30f;
        const bool diag = (kb == qb);
#pragma unroll
        for (int ts = 0; ts < 4; ++ts)
#pragma unroll
            for (int r = 0; r < 4; ++r) {
                float x = accS[ts][r] * C;
                if (diag && (16 * ts + 4 * quad + r) > qi_l) x = -1e30f;
                sv[4 * ts + r] = x;
                tmax = fmaxf(tmax, x);
            }
        tmax = fmaxf(tmax, __shfl_xor(tmax, 16));
        tmax = fmaxf(tmax, __shfl_xor(tmax, 32));
        float mnew  = fmaxf(m_r, tmax);
        float alpha = exp2f(m_r - mnew);
        float ssum  = 0.f;
#pragma unroll
        for (int i = 0; i < 16; ++i) {
            float p = exp2f(sv[i] - mnew);
            sv[i] = p; ssum += p;
        }
        ssum += __shfl_xor(ssum, 16);
        ssum += __shfl_xor(ssum, 32);
        l_r = alpha * l_r + ssum;
        m_r = mnew;

        // ---- pack P -> Ps[m][t] (wave-private rows; contiguous b64) ----
#pragma unroll
        for (int ts = 0; ts < 4; ++ts) {
            *(uint2*)&Ps[16 * w + l][16 * ts + 4 * quad] =
                make_uint2(pack2(sv[4 * ts + 0], sv[4 * ts + 1]),
                           pack2(sv[4 * ts + 2], sv[4 * ts + 3]));
        }

        // ---- rescale O by alpha (alpha lives at lane = m_local in quad 0) ----
#pragma unroll
        for (int r = 0; r < 4; ++r) {
            float ar = __shfl(alpha, (quad << 2) + r);
#pragma unroll
            for (int tn = 0; tn < 4; ++tn) accO[tn][r] *= ar;
        }

        // ---- O += P · V : A = Ps rows, B = Vts rows ----
        bf16x8 pa0 = *(const bf16x8*)&Ps[16 * w + l][quad * 8];
        bf16x8 pa1 = *(const bf16x8*)&Ps[16 * w + l][32 + quad * 8];
#pragma unroll
        for (int tn = 0; tn < 4; ++tn) {
            bf16x8 v0 = *(const bf16x8*)&Vts[16 * tn + l][quad * 8];
            bf16x8 v1 = *(const bf16x8*)&Vts[16 * tn + l][32 + quad * 8];
            accO[tn] = __builtin_amdgcn_mfma_f32_16x16x32_bf16(pa0, v0, accO[tn], 0, 0, 0);
            accO[tn] = __builtin_amdgcn_mfma_f32_16x16x32_bf16(pa1, v1, accO[tn], 0, 0, 0);
        }
    }

    // ---- finalize: O /= l, write fp32 (overwrites this block's Q region) ----
#pragma unroll
    for (int r = 0; r < 4; ++r) {
        float lr  = __shfl(l_r, (quad << 2) + r);
        float inv = 1.0f / lr;
        const int row = q0 + 16 * w + 4 * quad + r;
#pragma unroll
        for (int tn = 0; tn < 4; ++tn)
            Out[(size_t)(b * SEQ + row) * EMB + h * HD + 16 * tn + l] =
                accO[tn][r] * inv;
    }
}

extern "C" void kernel_launch(void* const* d_in, const int* in_sizes, int n_in,
                              void* d_out, int out_size, void* d_ws, size_t ws_size,
                              hipStream_t stream) {
    const float* X  = (const float*)d_in[0];
    const float* Wq = (const float*)d_in[1];
    const float* Wk = (const float*)d_in[2];
    const float* Wv = (const float*)d_in[3];
    float* OutP = (float*)d_out;

    // ws: K bf16 [4096][64] (512 KiB) + Vt bf16 [64][4096] (512 KiB)
    uint16_t* Kbf  = (uint16_t*)d_ws;
    uint16_t* Vtbf = Kbf + (size_t)BSZ * SEQ * HD;

    qkv_gemm<<<dim3(18, 64), 256, 0, stream>>>(X, Wq, Wk, Wv, OutP, Kbf, Vtbf);
    mqa_attn<<<dim3(SEQ / 64, NH, BSZ), 256, 0, stream>>>(Kbf, Vtbf, OutP);
}

// Round 6
// 199.641 us; speedup vs baseline: 4.0435x; 1.5344x over previous
//
#include <hip/hip_runtime.h>
#include <stdint.h>

#define NH   16
#define EMB  1024
#define HD   64
#define BSZ  2
#define SEQ  2048
#define NROW (BSZ * SEQ)          // 4096

typedef __attribute__((ext_vector_type(8))) short bf16x8;   // 8 bf16 = 4 VGPRs
typedef __attribute__((ext_vector_type(4))) float f32x4;    // MFMA C/D

__device__ __forceinline__ uint16_t f2bf(float f) {
    union { float f; uint32_t i; } v; v.f = f;
    uint32_t r = v.i + 0x7FFFu + ((v.i >> 16) & 1u);  // RNE
    return (uint16_t)(r >> 16);
}
__device__ __forceinline__ uint32_t pack2(float a, float b) {
    return (uint32_t)f2bf(a) | ((uint32_t)f2bf(b) << 16);
}

// =====================================================================
// Prep A: X fp32 -> bf16 (8 elems / thread)
// =====================================================================
__global__ __launch_bounds__(256) void convert_x(
    const float* __restrict__ X, uint16_t* __restrict__ Xbf)
{
    size_t idx = ((size_t)blockIdx.x * 256 + threadIdx.x) * 8;
    float4 a = *(const float4*)&X[idx];
    float4 b = *(const float4*)&X[idx + 4];
    *(uint4*)&Xbf[idx] = make_uint4(pack2(a.x, a.y), pack2(a.z, a.w),
                                    pack2(b.x, b.y), pack2(b.z, b.w));
}

// =====================================================================
// Prep B: W[k][n] fp32 -> Wt[n][k] bf16 (64x64 tiles via LDS).
// blocks 0..255 -> Wq, 256..271 -> Wk, 272..287 -> Wv.
// =====================================================================
__global__ __launch_bounds__(256) void transpose_w(
    const float* __restrict__ Wq, const float* __restrict__ Wk,
    const float* __restrict__ Wv, uint16_t* __restrict__ Wqt,
    uint16_t* __restrict__ Wkt, uint16_t* __restrict__ Wvt)
{
    const int id = blockIdx.x, tid = threadIdx.x;
    const float* W; uint16_t* Wt; int k0, n0, ldw;
    if (id < 256)      { W = Wq; Wt = Wqt; k0 = (id >> 4) * 64; n0 = (id & 15) * 64; ldw = EMB; }
    else if (id < 272) { W = Wk; Wt = Wkt; k0 = (id - 256) * 64; n0 = 0; ldw = HD; }
    else               { W = Wv; Wt = Wvt; k0 = (id - 272) * 64; n0 = 0; ldw = HD; }

    __shared__ uint16_t T[64][72];
    const int r = tid >> 2, c4 = (tid & 3) * 16;
#pragma unroll
    for (int i = 0; i < 4; ++i) {
        float4 wv = *(const float4*)&W[(size_t)(k0 + r) * ldw + n0 + c4 + 4 * i];
        T[r][c4 + 4 * i + 0] = f2bf(wv.x); T[r][c4 + 4 * i + 1] = f2bf(wv.y);
        T[r][c4 + 4 * i + 2] = f2bf(wv.z); T[r][c4 + 4 * i + 3] = f2bf(wv.w);
    }
    __syncthreads();
    const int n = tid >> 2, kk = (tid & 3) * 16;
    uint32_t o[8];
#pragma unroll
    for (int i = 0; i < 8; ++i)
        o[i] = (uint32_t)T[kk + 2 * i][n] | ((uint32_t)T[kk + 2 * i + 1][n] << 16);
    uint16_t* dst = &Wt[(size_t)(n0 + n) * EMB + k0 + kk];
    *(uint4*)dst       = make_uint4(o[0], o[1], o[2], o[3]);
    *(uint4*)(dst + 8) = make_uint4(o[4], o[5], o[6], o[7]);
}

// =====================================================================
// Kernel 1 (fast): MFMA projection GEMM, 128x128 tiles, BK=32.
// grid (9, 32): nt 0..7 -> Q col-tiles (fp32 -> d_out); nt 8 -> K|V
// (waves 0,1 -> K bf16 [t][d]; waves 2,3 -> V bf16 transposed Vt[d][t]).
// =====================================================================
__global__ __launch_bounds__(256) void qkv_gemm_mfma(
    const uint16_t* __restrict__ Xbf, const uint16_t* __restrict__ Wqt,
    const uint16_t* __restrict__ Wkt, const uint16_t* __restrict__ Wvt,
    float* __restrict__ Qout, uint16_t* __restrict__ Kbf,
    uint16_t* __restrict__ Vtbf)
{
    const int tid  = threadIdx.x;
    const int w    = tid >> 6, lane = tid & 63;
    const int l    = lane & 15, quad = lane >> 4;
    const int wm   = w & 1, wn = w >> 1;
    const int nt   = blockIdx.x;
    const int m0   = blockIdx.y * 128;

    __shared__ uint16_t As[128][40];   // X  tile [m][k]
    __shared__ uint16_t Bs[128][40];   // W^T tile [n][k]

    f32x4 acc[4][4] = {};

    const int sr = tid >> 1, kh = (tid & 1) * 16;   // staging row / k-half

    for (int k0 = 0; k0 < EMB; k0 += 32) {
        // ---- stage A: Xbf rows ----
        {
            const uint4* src = (const uint4*)&Xbf[(size_t)(m0 + sr) * EMB + k0 + kh];
            uint4 a0 = src[0], a1 = src[1];
            *(uint4*)&As[sr][kh] = a0; *(uint4*)&As[sr][kh + 8] = a1;
        }
        // ---- stage B: Wt rows ----
        {
            const uint16_t* src;
            if (nt < 8)       src = &Wqt[(size_t)(nt * 128 + sr) * EMB + k0 + kh];
            else if (sr < 64) src = &Wkt[(size_t)sr * EMB + k0 + kh];
            else              src = &Wvt[(size_t)(sr - 64) * EMB + k0 + kh];
            uint4 b0 = ((const uint4*)src)[0], b1 = ((const uint4*)src)[1];
            *(uint4*)&Bs[sr][kh] = b0; *(uint4*)&Bs[sr][kh + 8] = b1;
        }
        __syncthreads();

        bf16x8 af[4], bf[4];
#pragma unroll
        for (int i = 0; i < 4; ++i)
            af[i] = *(const bf16x8*)&As[64 * wm + 16 * i + l][quad * 8];
#pragma unroll
        for (int j = 0; j < 4; ++j)
            bf[j] = *(const bf16x8*)&Bs[64 * wn + 16 * j + l][quad * 8];
#pragma unroll
        for (int i = 0; i < 4; ++i)
#pragma unroll
            for (int j = 0; j < 4; ++j)
                acc[i][j] = __builtin_amdgcn_mfma_f32_16x16x32_bf16(
                    af[i], bf[j], acc[i][j], 0, 0, 0);
        __syncthreads();
    }

    // ---- epilogue.  C layout: col = l (n), row = quad*4 + r (m). ----
    if (nt < 8) {
#pragma unroll
        for (int i = 0; i < 4; ++i)
#pragma unroll
            for (int j = 0; j < 4; ++j)
#pragma unroll
                for (int r = 0; r < 4; ++r)
                    Qout[(size_t)(m0 + 64 * wm + 16 * i + 4 * quad + r) * EMB
                         + nt * 128 + 64 * wn + 16 * j + l] = acc[i][j][r];
    } else if (wn == 0) {     // K -> bf16 [t][d]
#pragma unroll
        for (int i = 0; i < 4; ++i)
#pragma unroll
            for (int j = 0; j < 4; ++j)
#pragma unroll
                for (int r = 0; r < 4; ++r)
                    Kbf[(size_t)(m0 + 64 * wm + 16 * i + 4 * quad + r) * HD
                        + 16 * j + l] = f2bf(acc[i][j][r]);
    } else {                  // V -> bf16 transposed Vt[d][t]
#pragma unroll
        for (int i = 0; i < 4; ++i)
#pragma unroll
            for (int j = 0; j < 4; ++j)
#pragma unroll
                for (int r = 0; r < 4; ++r)
                    Vtbf[(size_t)(16 * j + l) * NROW
                         + m0 + 64 * wm + 16 * i + 4 * quad + r] = f2bf(acc[i][j][r]);
    }
}

// =====================================================================
// Kernel 1 (fallback, proven R5): fp32 vector projection GEMM.
// =====================================================================
__global__ __launch_bounds__(256) void qkv_gemm_vec(
    const float* __restrict__ X,  const float* __restrict__ Wq,
    const float* __restrict__ Wk, const float* __restrict__ Wv,
    float* __restrict__ Qout, uint16_t* __restrict__ Kbf,
    uint16_t* __restrict__ Vtbf)
{
    const int tid = threadIdx.x;
    const int tx = tid & 15, ty = tid >> 4;
    const int bx = blockIdx.x;
    const int m0 = blockIdx.y * 64;

    const float* W; int ldw, n0;
    if (bx < 16)       { W = Wq; ldw = EMB; n0 = bx * 64; }
    else if (bx == 16) { W = Wk; ldw = HD;  n0 = 0; }
    else               { W = Wv; ldw = HD;  n0 = 0; }

    __shared__ float sA[64][17];
    __shared__ float sB[16][64];

    float acc[4][4] = {};
    const int arow = tid >> 2, acol = (tid & 3) * 4;
    const int brow = tid >> 4, bcol = (tid & 15) * 4;

    for (int k0 = 0; k0 < EMB; k0 += 16) {
        float4 fa = *(const float4*)&X[(size_t)(m0 + arow) * EMB + k0 + acol];
        float4 fb = *(const float4*)&W[(size_t)(k0 + brow) * ldw + n0 + bcol];
        sA[arow][acol + 0] = fa.x; sA[arow][acol + 1] = fa.y;
        sA[arow][acol + 2] = fa.z; sA[arow][acol + 3] = fa.w;
        sB[brow][bcol + 0] = fb.x; sB[brow][bcol + 1] = fb.y;
        sB[brow][bcol + 2] = fb.z; sB[brow][bcol + 3] = fb.w;
        __syncthreads();
#pragma unroll
        for (int kk = 0; kk < 16; ++kk) {
            float a0 = sA[4 * ty + 0][kk];
            float a1 = sA[4 * ty + 1][kk];
            float a2 = sA[4 * ty + 2][kk];
            float a3 = sA[4 * ty + 3][kk];
            float4 b = *(const float4*)&sB[kk][4 * tx];
            acc[0][0] += a0 * b.x; acc[0][1] += a0 * b.y; acc[0][2] += a0 * b.z; acc[0][3] += a0 * b.w;
            acc[1][0] += a1 * b.x; acc[1][1] += a1 * b.y; acc[1][2] += a1 * b.z; acc[1][3] += a1 * b.w;
            acc[2][0] += a2 * b.x; acc[2][1] += a2 * b.y; acc[2][2] += a2 * b.z; acc[2][3] += a2 * b.w;
            acc[3][0] += a3 * b.x; acc[3][1] += a3 * b.y; acc[3][2] += a3 * b.z; acc[3][3] += a3 * b.w;
        }
        __syncthreads();
    }

    if (bx < 16) {
#pragma unroll
        for (int i = 0; i < 4; ++i)
            *(float4*)&Qout[(size_t)(m0 + 4 * ty + i) * EMB + n0 + 4 * tx] =
                make_float4(acc[i][0], acc[i][1], acc[i][2], acc[i][3]);
    } else if (bx == 16) {
#pragma unroll
        for (int i = 0; i < 4; ++i) {
            ushort4 u; u.x = f2bf(acc[i][0]); u.y = f2bf(acc[i][1]);
            u.z = f2bf(acc[i][2]); u.w = f2bf(acc[i][3]);
            *(ushort4*)&Kbf[(size_t)(m0 + 4 * ty + i) * HD + 4 * tx] = u;
        }
    } else {
#pragma unroll
        for (int j = 0; j < 4; ++j) {
            ushort4 u; u.x = f2bf(acc[0][j]); u.y = f2bf(acc[1][j]);
            u.z = f2bf(acc[2][j]); u.w = f2bf(acc[3][j]);
            *(ushort4*)&Vtbf[(size_t)(4 * tx + j) * NROW + m0 + 4 * ty] = u;
        }
    }
}

// =====================================================================
// Kernel 2: causal MQA flash attention with bf16 MFMA (unchanged R5).
// =====================================================================
__global__ __launch_bounds__(256, 4) void mqa_attn(
    const uint16_t* __restrict__ Kbf, const uint16_t* __restrict__ Vtbf,
    float* __restrict__ Out)
{
    const int tid  = threadIdx.x;
    const int w    = tid >> 6;
    const int lane = tid & 63;
    const int l    = lane & 15;
    const int quad = lane >> 4;
    const int qb = blockIdx.x, h = blockIdx.y, b = blockIdx.z;
    const int q0 = qb * 64;

    __shared__ uint16_t Qs [64][72];
    __shared__ uint16_t Ks [64][72];
    __shared__ uint16_t Vts[64][72];
    __shared__ uint16_t Ps [64][72];

    {
        const int r = tid >> 2, c0 = (tid & 3) * 16;
        const float* src = &Out[(size_t)(b * SEQ + q0 + r) * EMB + h * HD + c0];
        float4 f0 = *(const float4*)(src + 0);
        float4 f1 = *(const float4*)(src + 4);
        float4 f2 = *(const float4*)(src + 8);
        float4 f3 = *(const float4*)(src + 12);
        *(uint4*)&Qs[r][c0] =
            make_uint4(pack2(f0.x, f0.y), pack2(f0.z, f0.w),
                       pack2(f1.x, f1.y), pack2(f1.z, f1.w));
        *(uint4*)&Qs[r][c0 + 8] =
            make_uint4(pack2(f2.x, f2.y), pack2(f2.z, f2.w),
                       pack2(f3.x, f3.y), pack2(f3.z, f3.w));
    }
    __syncthreads();

    bf16x8 qf0 = *(const bf16x8*)&Qs[16 * w + l][quad * 8];
    bf16x8 qf1 = *(const bf16x8*)&Qs[16 * w + l][32 + quad * 8];

    float m_r = -1e30f, l_r = 0.f;
    f32x4 accO[4] = {{0.f,0.f,0.f,0.f},{0.f,0.f,0.f,0.f},
                     {0.f,0.f,0.f,0.f},{0.f,0.f,0.f,0.f}};
    const float C = 0.125f * 1.4426950408889634f;
    const int qi_l = 16 * w + l;

    for (int kb = 0; kb <= qb; ++kb) {
        const int k0 = kb * 64;
        __syncthreads();
        {
            const int r = tid >> 2, c0 = (tid & 3) * 16;
            const uint4* ks = (const uint4*)&Kbf[(size_t)(b * SEQ + k0 + r) * HD + c0];
            uint4 k0v = ks[0], k1v = ks[1];
            *(uint4*)&Ks[r][c0] = k0v; *(uint4*)&Ks[r][c0 + 8] = k1v;
            const uint4* vs = (const uint4*)&Vtbf[(size_t)r * NROW + b * SEQ + k0 + c0];
            uint4 v0v = vs[0], v1v = vs[1];
            *(uint4*)&Vts[r][c0] = v0v; *(uint4*)&Vts[r][c0 + 8] = v1v;
        }
        __syncthreads();

        f32x4 accS[4] = {{0.f,0.f,0.f,0.f},{0.f,0.f,0.f,0.f},
                         {0.f,0.f,0.f,0.f},{0.f,0.f,0.f,0.f}};
#pragma unroll
        for (int ts = 0; ts < 4; ++ts) {
            bf16x8 a0 = *(const bf16x8*)&Ks[16 * ts + l][quad * 8];
            bf16x8 a1 = *(const bf16x8*)&Ks[16 * ts + l][32 + quad * 8];
            accS[ts] = __builtin_amdgcn_mfma_f32_16x16x32_bf16(a0, qf0, accS[ts], 0, 0, 0);
            accS[ts] = __builtin_amdgcn_mfma_f32_16x16x32_bf16(a1, qf1, accS[ts], 0, 0, 0);
        }

        float sv[16];
        float tmax = -1e30f;
        const bool diag = (kb == qb);
#pragma unroll
        for (int ts = 0; ts < 4; ++ts)
#pragma unroll
            for (int r = 0; r < 4; ++r) {
                float x = accS[ts][r] * C;
                if (diag && (16 * ts + 4 * quad + r) > qi_l) x = -1e30f;
                sv[4 * ts + r] = x;
                tmax = fmaxf(tmax, x);
            }
        tmax = fmaxf(tmax, __shfl_xor(tmax, 16));
        tmax = fmaxf(tmax, __shfl_xor(tmax, 32));
        float mnew  = fmaxf(m_r, tmax);
        float alpha = exp2f(m_r - mnew);
        float ssum  = 0.f;
#pragma unroll
        for (int i = 0; i < 16; ++i) {
            float p = exp2f(sv[i] - mnew);
            sv[i] = p; ssum += p;
        }
        ssum += __shfl_xor(ssum, 16);
        ssum += __shfl_xor(ssum, 32);
        l_r = alpha * l_r + ssum;
        m_r = mnew;

#pragma unroll
        for (int ts = 0; ts < 4; ++ts) {
            *(uint2*)&Ps[16 * w + l][16 * ts + 4 * quad] =
                make_uint2(pack2(sv[4 * ts + 0], sv[4 * ts + 1]),
                           pack2(sv[4 * ts + 2], sv[4 * ts + 3]));
        }

#pragma unroll
        for (int r = 0; r < 4; ++r) {
            float ar = __shfl(alpha, (quad << 2) + r);
#pragma unroll
            for (int tn = 0; tn < 4; ++tn) accO[tn][r] *= ar;
        }

        bf16x8 pa0 = *(const bf16x8*)&Ps[16 * w + l][quad * 8];
        bf16x8 pa1 = *(const bf16x8*)&Ps[16 * w + l][32 + quad * 8];
#pragma unroll
        for (int tn = 0; tn < 4; ++tn) {
            bf16x8 v0 = *(const bf16x8*)&Vts[16 * tn + l][quad * 8];
            bf16x8 v1 = *(const bf16x8*)&Vts[16 * tn + l][32 + quad * 8];
            accO[tn] = __builtin_amdgcn_mfma_f32_16x16x32_bf16(pa0, v0, accO[tn], 0, 0, 0);
            accO[tn] = __builtin_amdgcn_mfma_f32_16x16x32_bf16(pa1, v1, accO[tn], 0, 0, 0);
        }
    }

#pragma unroll
    for (int r = 0; r < 4; ++r) {
        float lr  = __shfl(l_r, (quad << 2) + r);
        float inv = 1.0f / lr;
        const int row = q0 + 16 * w + 4 * quad + r;
#pragma unroll
        for (int tn = 0; tn < 4; ++tn)
            Out[(size_t)(b * SEQ + row) * EMB + h * HD + 16 * tn + l] =
                accO[tn][r] * inv;
    }
}

extern "C" void kernel_launch(void* const* d_in, const int* in_sizes, int n_in,
                              void* d_out, int out_size, void* d_ws, size_t ws_size,
                              hipStream_t stream) {
    const float* X  = (const float*)d_in[0];
    const float* Wq = (const float*)d_in[1];
    const float* Wk = (const float*)d_in[2];
    const float* Wv = (const float*)d_in[3];
    float* OutP = (float*)d_out;

    // Fast-path ws layout (bytes):
    //   Xbf  [4096][1024] bf16   8 MiB   @ 0
    //   Wqt  [1024][1024] bf16   2 MiB   @ 8 MiB
    //   Wkt  [64][1024]   bf16 128 KiB   @ 10 MiB
    //   Wvt  [64][1024]   bf16 128 KiB   @ 10.25 MiB
    //   Kbf  [4096][64]   bf16 512 KiB   @ 10.5 MiB
    //   Vtbf [64][4096]   bf16 512 KiB   @ 11 MiB      (total 11.5 MiB)
    char* ws = (char*)d_ws;
    const size_t MB = 1024 * 1024;
    uint16_t* Xbf  = (uint16_t*)(ws);
    uint16_t* Wqt  = (uint16_t*)(ws + 8 * MB);
    uint16_t* Wkt  = (uint16_t*)(ws + 10 * MB);
    uint16_t* Wvt  = (uint16_t*)(ws + 10 * MB + 256 * 1024);
    uint16_t* KbfF = (uint16_t*)(ws + 10 * MB + 512 * 1024);
    uint16_t* VtbfF= (uint16_t*)(ws + 11 * MB);

    if (ws_size >= 12 * MB) {
        convert_x  <<<2048, 256, 0, stream>>>(X, Xbf);
        transpose_w<<<288, 256, 0, stream>>>(Wq, Wk, Wv, Wqt, Wkt, Wvt);
        qkv_gemm_mfma<<<dim3(9, 32), 256, 0, stream>>>(Xbf, Wqt, Wkt, Wvt,
                                                       OutP, KbfF, VtbfF);
        mqa_attn<<<dim3(SEQ / 64, NH, BSZ), 256, 0, stream>>>(KbfF, VtbfF, OutP);
    } else {
        // Fallback (proven R5 path, needs 1 MiB ws)
        uint16_t* Kbf  = (uint16_t*)d_ws;
        uint16_t* Vtbf = Kbf + (size_t)NROW * HD;
        qkv_gemm_vec<<<dim3(18, 64), 256, 0, stream>>>(X, Wq, Wk, Wv, OutP, Kbf, Vtbf);
        mqa_attn<<<dim3(SEQ / 64, NH, BSZ), 256, 0, stream>>>(Kbf, Vtbf, OutP);
    }
}